// Round 13
// baseline (2134.516 us; speedup 1.0000x reference)
//
#include <hip/hip_runtime.h>
#include <hip/hip_bf16.h>
#include <math.h>

#define BB 64
#define TT 200
#define DD 256
#define HH 512
#define NCOL 3584  // 7*H
#define NB 32      // blocks in recurrent kernel

using bf16x8  = __attribute__((ext_vector_type(8))) short;
using f32x4   = __attribute__((ext_vector_type(4))) float;
using f32x16  = __attribute__((ext_vector_type(16))) float;

// ---- fast device math ----
__device__ __forceinline__ float frcp_(float x) { return __builtin_amdgcn_rcpf(x); }
__device__ __forceinline__ float sigmoidf_(float x) {
    return frcp_(1.0f + __expf(-x));
}
__device__ __forceinline__ float tanhf_(float x) {
    return 1.0f - 2.0f * frcp_(__expf(2.0f * x) + 1.0f);
}
__device__ __forceinline__ float softplusf_(float x) {
    return fmaxf(x, 0.0f) + __logf(1.0f + __expf(-fabsf(x)));
}
__device__ __forceinline__ short f2bf(float f) {
    union { float f; unsigned u; } v; v.f = f;
    unsigned r = v.u + 0x7fff + ((v.u >> 16) & 1);  // RNE
    return (short)(r >> 16);
}
__device__ __forceinline__ float bf2f(short s) {
    union { unsigned u; float f; } v; v.u = ((unsigned)(unsigned short)s) << 16;
    return v.f;
}

// input (B,T,D) fp32 -> Xbf (B*T, D) bf16
__global__ __launch_bounds__(256) void convert_x_kernel(
    const float* __restrict__ in, short* __restrict__ Xbf)
{
    int idx = blockIdx.x * 256 + threadIdx.x;  // < 819200
    float4 v = ((const float4*)in)[idx];
    short4 s;
    s.x = f2bf(v.x); s.y = f2bf(v.y); s.z = f2bf(v.z); s.w = f2bf(v.w);
    ((short4*)Xbf)[idx] = s;
}

// Wx (D, NCOL) fp32 -> WxP packed B-fragments (16x16x32 convention)
__global__ __launch_bounds__(256) void pack_wx_kernel(
    const float* __restrict__ Wx, short* __restrict__ WxP)
{
    int idx = blockIdx.x * 256 + threadIdx.x;  // < 917504
    int jj = idx & 7, lane = (idx >> 3) & 63, kt = (idx >> 9) & 7, nt = idx >> 12;
    int k = kt * 32 + ((lane >> 4) << 3) + jj;
    int col = nt * 16 + (lane & 15);
    WxP[idx] = f2bf(Wx[(size_t)k * NCOL + col]);
}

// Wh (H, NCOL) fp32 -> WhP2 packed 32x32x16 A-fragments.
// Layout [j0][rt][kt][lane][jj]: row-space rho=lane&31 -> g=rho&7, hc=rho>>3
// (8 gate slots, g==7 zero pad); k = kt*16 + (lane>>5)*8 + jj;
// hcol = j0*16 + rt*4 + hc.
__global__ __launch_bounds__(256) void pack_wh2_kernel(
    const float* __restrict__ Wh, short* __restrict__ WhP2)
{
    int idx = blockIdx.x * 256 + threadIdx.x;  // < 2,097,152
    int jj = idx & 7, lane = (idx >> 3) & 63, kt = (idx >> 9) & 31;
    int rt = (idx >> 14) & 3, j0 = idx >> 16;
    int rho = lane & 31, half = lane >> 5;
    int g = rho & 7, hc = rho >> 3;
    int k = kt * 16 + half * 8 + jj;
    int hcol = j0 * 16 + rt * 4 + hc;
    WhP2[idx] = (g < 7) ? f2bf(Wh[(size_t)k * NCOL + g * HH + hcol]) : (short)0;
}

// GEMM1: Xb[row][col] = bf16( Xbf(row,:) @ Wx(:,col) + bias[col] )
__global__ __launch_bounds__(256) void precompute_kernel(
    const short* __restrict__ Xbf, const short* __restrict__ WxP,
    const float* __restrict__ bias, short* __restrict__ Xb)
{
    const int tid = threadIdx.x;
    const int lane = tid & 63;
    const int w = tid >> 6;
    const int nb = blockIdx.x;   // 0..55
    const int mb = blockIdx.y;   // 0..199

    f32x4 acc[4];
    #pragma unroll
    for (int i = 0; i < 4; ++i) acc[i] = (f32x4){0.f, 0.f, 0.f, 0.f};

    const int rowA = mb * 64 + w * 16 + (lane & 15);
    const short* __restrict__ ha = Xbf + (size_t)rowA * DD + ((lane >> 4) << 3);
    const short* __restrict__ wbase = WxP + ((size_t)(nb * 4) * 512 + lane) * 8;

    #pragma unroll 2
    for (int kt = 0; kt < 8; ++kt) {
        bf16x8 a = *(const bf16x8*)(ha + kt * 32);
        #pragma unroll
        for (int i = 0; i < 4; ++i) {
            bf16x8 b = *(const bf16x8*)(wbase + i * 4096 + kt * 512);
            acc[i] = __builtin_amdgcn_mfma_f32_16x16x32_bf16(a, b, acc[i], 0, 0, 0);
        }
    }

    const int colL = lane & 15;
    const int rBase = mb * 64 + w * 16 + ((lane >> 4) << 2);
    #pragma unroll
    for (int i = 0; i < 4; ++i) {
        const int col = (nb * 4 + i) * 16 + colL;
        const float bv = bias[col];
        #pragma unroll
        for (int r = 0; r < 4; ++r) {
            Xb[(size_t)(rBase + r) * NCOL + col] = f2bf(acc[i][r] + bv);
        }
    }
}

// Persistent recurrent kernel: 32 blocks x 256 thr, all 200 steps.
// R9's sync protocol VERBATIM (per-block replicated flags, wave0 poll with
// s_sleep). GEMM restructured to 32x32x16 MFMA: wave = 2 rowtiles x 1
// coltile(32 batches); block LDS A-reads drop 448KB -> 256KB per step.
// Gate halves exchanged with 16 shfl_xor(.,32); epilogue shape unchanged.
__global__ __launch_bounds__(256, 1) void recurrent_kernel(
    const short* __restrict__ Xb,           // (B*T, NCOL) bf16
    const short* __restrict__ WhP2,         // packed 32x32 A-frags
    const float* __restrict__ dur,          // (B, T)
    unsigned long long* __restrict__ h0,    // (B, H) bf16, u64 view
    unsigned long long* __restrict__ h1,
    unsigned* __restrict__ flags,           // [TT][8 replicas][32 blocks]
    float* __restrict__ out)                // (4, B, T, H)
{
    __shared__ short whL[4 * 32 * 64 * 8];  // [rt][kt][lane][jj] = 131072 B

    const int tid = threadIdx.x;
    const int lane = tid & 63;
    const int w = tid >> 6;
    const int j0 = blockIdx.x;

    // ---- stage Wh block slice into LDS (one time, 128 KB) ----
    {
        const bf16x8* __restrict__ src = (const bf16x8*)(WhP2 + (size_t)j0 * 65536);
        bf16x8* dst = (bf16x8*)whL;
        #pragma unroll
        for (int i = 0; i < 32; ++i) dst[i * 256 + tid] = src[i * 256 + tid];
    }
    __syncthreads();

    const int ct   = w & 1;          // coltile: batches ct*32..+32
    const int rtp  = w >> 1;         // rowtile pair: rt {2rtp, 2rtp+1}
    const int half = lane >> 5;
    const int b = ct * 32 + (lane & 31);
    const int hcolBase = j0 * 16 + rtp * 8 + half * 4;
    const int rt0 = rtp * 2, rt1 = rtp * 2 + 1;
    const size_t hB64base = (size_t)b * 128 + half * 2;  // u64 idx: (b*512+half*8)/4
    const short* __restrict__ wl = whL + lane * 8;       // + rt*16384 + kt*512
    const int myrep = j0 & 7;

    float cdecr[4] = {0.f, 0.f, 0.f, 0.f};
    float cbarr[4] = {0.f, 0.f, 0.f, 0.f};
    const size_t S = (size_t)BB * TT * HH;

    // ---- prefetch t=0 gate row + dt ----
    unsigned long long xq[7];
    {
        const unsigned long long* xb64 =
            (const unsigned long long*)(Xb + (size_t)b * TT * NCOL + hcolBase);
        #pragma unroll
        for (int g = 0; g < 7; ++g) xq[g] = xb64[g * (HH / 4)];
    }
    float dtn = dur[b * TT + 1];

    #pragma unroll 1
    for (int t = 0; t < TT; ++t) {
        // ---- acquire h_t: wave0 polls per-block flags, barrier, h burst ----
        unsigned long long hr[64];
        f32x16 acc0 = {0.f,0.f,0.f,0.f,0.f,0.f,0.f,0.f,0.f,0.f,0.f,0.f,0.f,0.f,0.f,0.f};
        f32x16 acc1 = {0.f,0.f,0.f,0.f,0.f,0.f,0.f,0.f,0.f,0.f,0.f,0.f,0.f,0.f,0.f,0.f};

        if (t > 0) {
            if (w == 0) {
                const unsigned* fl = flags + ((size_t)(t - 1) * 8 + myrep) * 32;
                while (true) {
                    unsigned f = (lane < 32)
                        ? __hip_atomic_load(fl + lane, __ATOMIC_RELAXED,
                                            __HIP_MEMORY_SCOPE_AGENT)
                        : 1u;
                    if (__all((int)(f != 0))) break;
                    __builtin_amdgcn_s_sleep(1);
                }
            }
            __syncthreads();
            const unsigned long long* hin = (t & 1) ? h1 : h0;
            #pragma unroll
            for (int kt = 0; kt < 32; ++kt) {
                hr[2 * kt]     = __hip_atomic_load(&hin[hB64base + kt * 4],
                                    __ATOMIC_RELAXED, __HIP_MEMORY_SCOPE_AGENT);
                hr[2 * kt + 1] = __hip_atomic_load(&hin[hB64base + kt * 4 + 1],
                                    __ATOMIC_RELAXED, __HIP_MEMORY_SCOPE_AGENT);
            }

            // ---- GEMM: 64 MFMAs of 32x32x16 per wave ----
            #pragma unroll
            for (int kt = 0; kt < 32; ++kt) {
                union { unsigned long long q[2]; bf16x8 v; } u;
                u.q[0] = hr[2 * kt]; u.q[1] = hr[2 * kt + 1];
                bf16x8 a0 = *(const bf16x8*)(wl + rt0 * 16384 + kt * 512);
                acc0 = __builtin_amdgcn_mfma_f32_32x32x16_bf16(a0, u.v, acc0, 0, 0, 0);
                bf16x8 a1 = *(const bf16x8*)(wl + rt1 * 16384 + kt * 512);
                acc1 = __builtin_amdgcn_mfma_f32_32x32x16_bf16(a1, u.v, acc1, 0, 0, 0);
            }
        }

        // ---- exchange gate halves: lane L keeps rt0 (lane<32) / rt1 ----
        // tmp = the tile I give away; recv = partner's complementary tile.
        float gLo[16], gHi[16];
        #pragma unroll
        for (int r = 0; r < 16; ++r) {
            float tmp = (lane < 32) ? acc1[r] : acc0[r];
            float recv = __shfl_xor(tmp, 32, 64);
            gLo[r] = (lane < 32) ? acc0[r] : recv;   // gates 0..3, hc=r>>2
            gHi[r] = (lane < 32) ? recv    : acc1[r];// gates 4..7, hc=r>>2
        }

        // ---- prefetch t+1 gate row + dt (overlaps epilogue) ----
        unsigned long long xqn[7];
        float dtnn;
        {
            const int tn = (t + 1 < TT) ? t + 1 : t;
            const unsigned long long* xb64n =
                (const unsigned long long*)(Xb + ((size_t)b * TT + tn) * NCOL + hcolBase);
            #pragma unroll
            for (int g = 0; g < 7; ++g) xqn[g] = xb64n[g * (HH / 4)];
            const int tn1 = (tn + 1 < TT) ? tn + 1 : TT - 1;
            dtnn = dur[b * TT + tn1];
        }

        // ---- epilogue (per lane: batch b, hcols hcolBase..+3) ----
        f32x4 oc, ocb, od, oo;
        unsigned long long hq = 0ull;
        #pragma unroll
        for (int q = 0; q < 4; ++q) {
            const float gi  = gLo[q * 4 + 0] + bf2f((short)(xq[0] >> (16 * q)));
            const float gf  = gLo[q * 4 + 1] + bf2f((short)(xq[1] >> (16 * q)));
            const float gz  = gLo[q * 4 + 2] + bf2f((short)(xq[2] >> (16 * q)));
            const float go  = gLo[q * 4 + 3] + bf2f((short)(xq[3] >> (16 * q)));
            const float gib = gHi[q * 4 + 0] + bf2f((short)(xq[4] >> (16 * q)));
            const float gfb = gHi[q * 4 + 1] + bf2f((short)(xq[5] >> (16 * q)));
            const float gd  = gHi[q * 4 + 2] + bf2f((short)(xq[6] >> (16 * q)));

            const float i_  = sigmoidf_(gi);
            const float f_  = sigmoidf_(gf);
            const float z_  = tanhf_(gz);
            const float o_  = sigmoidf_(go);
            const float ib_ = sigmoidf_(gib);
            const float fb_ = sigmoidf_(gfb);
            const float d_  = softplusf_(gd);

            const float c_new  = f_ * cdecr[q] + i_ * z_;
            const float cb_new = fb_ * cbarr[q] + ib_ * z_;

            oc[q] = c_new; ocb[q] = cb_new; od[q] = d_; oo[q] = o_;

            const float cdn = cb_new + (c_new - cb_new) * __expf(-d_ * dtn);
            const float hn = o_ * tanhf_(cdn);
            cdecr[q] = cdn;
            cbarr[q] = cb_new;
            hq |= ((unsigned long long)(unsigned short)f2bf(hn)) << (16 * q);
        }

        // ---- publish h_{t+1}: store; __syncthreads drains every wave's
        //      h store; then ONE block flag into 8 replicas ----
        if (t + 1 < TT) {
            unsigned long long* hout = (t & 1) ? h0 : h1;
            __hip_atomic_store(&hout[((size_t)b * HH + hcolBase) >> 2], hq,
                               __ATOMIC_RELAXED, __HIP_MEMORY_SCOPE_AGENT);
            __syncthreads();
            if (w == 0 && lane < 8) {
                __hip_atomic_store(&flags[((size_t)t * 8 + lane) * 32 + j0], 1u,
                                   __ATOMIC_RELAXED, __HIP_MEMORY_SCOPE_AGENT);
            }
        }

        // ---- out stores (after flag; retire during next poll) ----
        const size_t ob = ((size_t)b * TT + t) * HH + hcolBase;
        *(f32x4*)(out + ob)         = oc;
        *(f32x4*)(out + ob + S)     = ocb;
        *(f32x4*)(out + ob + 2 * S) = od;
        *(f32x4*)(out + ob + 3 * S) = oo;

        #pragma unroll
        for (int g = 0; g < 7; ++g) xq[g] = xqn[g];
        dtn = dtnn;
    }
}

extern "C" void kernel_launch(void* const* d_in, const int* in_sizes, int n_in,
                              void* d_out, int out_size, void* d_ws, size_t ws_size,
                              hipStream_t stream) {
    const float* input = (const float*)d_in[0];  // (B, T, D)
    const float* dur   = (const float*)d_in[1];  // (B, T)
    const float* Wx    = (const float*)d_in[2];  // (D, 7H)
    const float* Wh    = (const float*)d_in[3];  // (H, 7H)
    const float* bias  = (const float*)d_in[4];  // (7H,)
    float* out = (float*)d_out;                  // (4, B, T, H)

    short* Xb   = (short*)d_ws;                      // 45,875,200 shorts
    short* Xbf  = Xb + (size_t)TT * BB * NCOL;       // 3,276,800
    short* WxP  = Xbf + (size_t)BB * TT * DD;        // 917,504
    short* WhP2 = WxP + 224 * 8 * 64 * 8;            // 2,097,152
    short* h0s  = WhP2 + (size_t)32 * 4 * 32 * 64 * 8;  // 32,768
    short* h1s  = h0s + BB * HH;                     // 32,768
    unsigned* flags = (unsigned*)(h1s + BB * HH);    // TT*8*32 u32

    // flags must start zeroed every launch (h bufs never read before write)
    hipMemsetAsync(flags, 0, (size_t)TT * 8 * 32 * sizeof(unsigned), stream);

    convert_x_kernel<<<3200, 256, 0, stream>>>(input, Xbf);
    pack_wx_kernel<<<3584, 256, 0, stream>>>(Wx, WxP);
    pack_wh2_kernel<<<8192, 256, 0, stream>>>(Wh, WhP2);

    precompute_kernel<<<dim3(56, 200), 256, 0, stream>>>(Xbf, WxP, bias, Xb);

    recurrent_kernel<<<NB, 256, 0, stream>>>(
        Xb, WhP2, dur,
        (unsigned long long*)h0s, (unsigned long long*)h1s,
        flags, out);
}

// Round 14
// 851.777 us; speedup vs baseline: 2.5060x; 2.5060x over previous
//
#include <hip/hip_runtime.h>
#include <hip/hip_bf16.h>
#include <math.h>

#define BB 64
#define TT 200
#define DD 256
#define HH 512
#define NCOL 3584  // 7*H
#define NGRP 4     // independent batch groups (16 batches each)
#define NBLK (NGRP * 32)  // recurrent blocks, 1 wave each

using bf16x8 = __attribute__((ext_vector_type(8))) short;
using f32x4  = __attribute__((ext_vector_type(4))) float;

// ---- fast device math ----
__device__ __forceinline__ float frcp_(float x) { return __builtin_amdgcn_rcpf(x); }
__device__ __forceinline__ float sigmoidf_(float x) {
    return frcp_(1.0f + __expf(-x));
}
__device__ __forceinline__ float tanhf_(float x) {
    return 1.0f - 2.0f * frcp_(__expf(2.0f * x) + 1.0f);
}
__device__ __forceinline__ float softplusf_(float x) {
    return fmaxf(x, 0.0f) + __logf(1.0f + __expf(-fabsf(x)));
}
__device__ __forceinline__ short f2bf(float f) {
    union { float f; unsigned u; } v; v.f = f;
    unsigned r = v.u + 0x7fff + ((v.u >> 16) & 1);  // RNE
    return (short)(r >> 16);
}
__device__ __forceinline__ float bf2f(short s) {
    union { unsigned u; float f; } v; v.u = ((unsigned)(unsigned short)s) << 16;
    return v.f;
}

// input (B,T,D) fp32 -> Xbf (B*T, D) bf16
__global__ __launch_bounds__(256) void convert_x_kernel(
    const float* __restrict__ in, short* __restrict__ Xbf)
{
    int idx = blockIdx.x * 256 + threadIdx.x;  // < 819200
    float4 v = ((const float4*)in)[idx];
    short4 s;
    s.x = f2bf(v.x); s.y = f2bf(v.y); s.z = f2bf(v.z); s.w = f2bf(v.w);
    ((short4*)Xbf)[idx] = s;
}

// Wx (D, NCOL) fp32 -> WxP packed B-fragments
__global__ __launch_bounds__(256) void pack_wx_kernel(
    const float* __restrict__ Wx, short* __restrict__ WxP)
{
    int idx = blockIdx.x * 256 + threadIdx.x;  // < 917504
    int jj = idx & 7, lane = (idx >> 3) & 63, kt = (idx >> 9) & 7, nt = idx >> 12;
    int k = kt * 32 + ((lane >> 4) << 3) + jj;
    int col = nt * 16 + (lane & 15);
    WxP[idx] = f2bf(Wx[(size_t)k * NCOL + col]);
}

// Wh (H, NCOL) fp32 -> WhP packed A-fragments grouped per (j0, gate)
__global__ __launch_bounds__(256) void pack_wh_kernel(
    const float* __restrict__ Wh, short* __restrict__ WhP)
{
    int idx = blockIdx.x * 256 + threadIdx.x;  // < 1835008
    int jj = idx & 7, lane = (idx >> 3) & 63, kt = (idx >> 9) & 15;
    int gj = idx >> 13;  // j0*7 + g
    int g = gj % 7, j0 = gj / 7;
    int k = kt * 32 + ((lane >> 4) << 3) + jj;
    int col = g * HH + j0 * 16 + (lane & 15);
    WhP[idx] = f2bf(Wh[(size_t)k * NCOL + col]);
}

// GEMM1: Xb[row][col] = bf16( Xbf(row,:) @ Wx(:,col) + bias[col] )
// Widened: each block does 64 rows x 128 cols (8 acc frags/wave, 2x ILP).
__global__ __launch_bounds__(256) void precompute_kernel(
    const short* __restrict__ Xbf, const short* __restrict__ WxP,
    const float* __restrict__ bias, short* __restrict__ Xb)
{
    const int tid = threadIdx.x;
    const int lane = tid & 63;
    const int w = tid >> 6;
    const int nb = blockIdx.x;   // 0..27
    const int mb = blockIdx.y;   // 0..199

    f32x4 acc[8];
    #pragma unroll
    for (int i = 0; i < 8; ++i) acc[i] = (f32x4){0.f, 0.f, 0.f, 0.f};

    const int rowA = mb * 64 + w * 16 + (lane & 15);
    const short* __restrict__ ha = Xbf + (size_t)rowA * DD + ((lane >> 4) << 3);
    const short* __restrict__ wbase = WxP + ((size_t)(nb * 8) * 512 + lane) * 8;

    #pragma unroll
    for (int kt = 0; kt < 8; ++kt) {
        bf16x8 a = *(const bf16x8*)(ha + kt * 32);
        #pragma unroll
        for (int i = 0; i < 8; ++i) {
            bf16x8 b = *(const bf16x8*)(wbase + i * 4096 + kt * 512);
            acc[i] = __builtin_amdgcn_mfma_f32_16x16x32_bf16(a, b, acc[i], 0, 0, 0);
        }
    }

    const int colL = lane & 15;
    const int rBase = mb * 64 + w * 16 + ((lane >> 4) << 2);
    #pragma unroll
    for (int i = 0; i < 8; ++i) {
        const int col = (nb * 8 + i) * 16 + colL;
        const float bv = bias[col];
        #pragma unroll
        for (int r = 0; r < 4; ++r) {
            Xb[(size_t)(rBase + r) * NCOL + col] = f2bf(acc[i][r] + bv);
        }
    }
}

// Persistent recurrent kernel: 128 single-wave blocks = 4 independent
// groups x 32 blocks. Group g owns batches g*16..+15; groups never sync
// with each other (disjoint h rows, disjoint flag lines). Within a group:
// R9's protocol verbatim (8-replica per-block flags, poll with s_sleep).
// Per-CU LDS A-traffic drops 448KB -> 112KB per step (batch split; the
// A-fragments are batch-independent so per-wave work is unchanged).
__global__ __launch_bounds__(64, 1) void recurrent_kernel(
    const short* __restrict__ Xb,           // (B*T, NCOL) bf16
    const short* __restrict__ WhP,          // packed A-frags
    const float* __restrict__ dur,          // (B, T)
    unsigned long long* __restrict__ h0,    // (B, H) bf16, u64 view
    unsigned long long* __restrict__ h1,
    unsigned* __restrict__ flags,           // [TT][NGRP][8 reps][32 blocks]
    float* __restrict__ out)                // (4, B, T, H)
{
    __shared__ short whL[7 * 16 * 64 * 8];  // 114688 B

    const int lane = threadIdx.x;           // single wave
    const int grp = blockIdx.x >> 5;        // 0..3
    const int j0 = blockIdx.x & 31;         // hcol tile

    // ---- stage Wh block slice into LDS (one time) ----
    {
        const bf16x8* __restrict__ src = (const bf16x8*)(WhP + (size_t)j0 * 57344);
        bf16x8* dst = (bf16x8*)whL;
        #pragma unroll
        for (int i = 0; i < 112; ++i) dst[i * 64 + lane] = src[i * 64 + lane];
    }
    __syncthreads();

    const int colL = lane & 15;
    const int b = grp * 16 + colL;                    // fixed batch per lane
    const int hcolBase = j0 * 16 + ((lane >> 4) << 2);
    const int kOff = (lane >> 4) << 3;                // 0,8,16,24
    const size_t hB64base = ((size_t)b * HH + kOff) >> 2;  // u64 index
    const short* __restrict__ wlds = whL + lane * 8;  // + g*8192 + kt*512
    const int myrep = j0 & 7;

    float cdecr[4] = {0.f, 0.f, 0.f, 0.f};
    float cbarr[4] = {0.f, 0.f, 0.f, 0.f};
    const size_t S = (size_t)BB * TT * HH;

    // ---- prefetch t=0 gate row + dt ----
    unsigned long long xq[7];
    {
        const unsigned long long* xb64 =
            (const unsigned long long*)(Xb + (size_t)b * TT * NCOL + hcolBase);
        #pragma unroll
        for (int g = 0; g < 7; ++g) xq[g] = xb64[g * (HH / 4)];
    }
    float dtn = dur[b * TT + 1];

    #pragma unroll 1
    for (int t = 0; t < TT; ++t) {
        // ---- acquire h_t: poll group's per-block flags, then h burst ----
        unsigned long long hr[32];
        if (t > 0) {
            const unsigned* fl =
                flags + (((size_t)(t - 1) * NGRP + grp) * 8 + myrep) * 32;
            while (true) {
                unsigned f = (lane < 32)
                    ? __hip_atomic_load(fl + lane, __ATOMIC_RELAXED,
                                        __HIP_MEMORY_SCOPE_AGENT)
                    : 1u;
                if (__all((int)(f != 0))) break;
                __builtin_amdgcn_s_sleep(1);
            }
            const unsigned long long* hin = (t & 1) ? h1 : h0;
            #pragma unroll
            for (int kt = 0; kt < 16; ++kt) {
                hr[2 * kt]     = __hip_atomic_load(&hin[hB64base + kt * 8],
                                    __ATOMIC_RELAXED, __HIP_MEMORY_SCOPE_AGENT);
                hr[2 * kt + 1] = __hip_atomic_load(&hin[hB64base + kt * 8 + 1],
                                    __ATOMIC_RELAXED, __HIP_MEMORY_SCOPE_AGENT);
            }
        } else {
            #pragma unroll
            for (int i = 0; i < 32; ++i) hr[i] = 0ull;
        }

        // ---- GEMM: 112 MFMAs, A from LDS, B from hr regs ----
        f32x4 acc[7];
        #pragma unroll
        for (int g = 0; g < 7; ++g) acc[g] = (f32x4){0.f, 0.f, 0.f, 0.f};

        #pragma unroll
        for (int kt = 0; kt < 16; ++kt) {
            union { unsigned long long q[2]; bf16x8 v; } u;
            u.q[0] = hr[2 * kt]; u.q[1] = hr[2 * kt + 1];
            const short* wkt = wlds + kt * 512;
            #pragma unroll
            for (int g = 0; g < 7; ++g) {
                bf16x8 a = *(const bf16x8*)(wkt + g * 8192);
                acc[g] = __builtin_amdgcn_mfma_f32_16x16x32_bf16(a, u.v, acc[g], 0, 0, 0);
            }
        }

        // ---- prefetch t+1 gate row + dt (overlaps epilogue; retires
        //      before the publish drain) ----
        unsigned long long xqn[7];
        float dtnn;
        {
            const int tn = (t + 1 < TT) ? t + 1 : t;
            const unsigned long long* xb64n =
                (const unsigned long long*)(Xb + ((size_t)b * TT + tn) * NCOL + hcolBase);
            #pragma unroll
            for (int g = 0; g < 7; ++g) xqn[g] = xb64n[g * (HH / 4)];
            const int tn1 = (tn + 1 < TT) ? tn + 1 : TT - 1;
            dtnn = dur[b * TT + tn1];
        }

        // ---- epilogue (per lane: batch b, hcols hcolBase..+3) ----
        f32x4 oc, ocb, od, oo;
        unsigned long long hq = 0ull;
        #pragma unroll
        for (int r = 0; r < 4; ++r) {
            const float gi  = acc[0][r] + bf2f((short)(xq[0] >> (16 * r)));
            const float gf  = acc[1][r] + bf2f((short)(xq[1] >> (16 * r)));
            const float gz  = acc[2][r] + bf2f((short)(xq[2] >> (16 * r)));
            const float go  = acc[3][r] + bf2f((short)(xq[3] >> (16 * r)));
            const float gib = acc[4][r] + bf2f((short)(xq[4] >> (16 * r)));
            const float gfb = acc[5][r] + bf2f((short)(xq[5] >> (16 * r)));
            const float gd  = acc[6][r] + bf2f((short)(xq[6] >> (16 * r)));

            const float i_  = sigmoidf_(gi);
            const float f_  = sigmoidf_(gf);
            const float z_  = tanhf_(gz);
            const float o_  = sigmoidf_(go);
            const float ib_ = sigmoidf_(gib);
            const float fb_ = sigmoidf_(gfb);
            const float d_  = softplusf_(gd);

            const float c_new  = f_ * cdecr[r] + i_ * z_;
            const float cb_new = fb_ * cbarr[r] + ib_ * z_;

            oc[r] = c_new; ocb[r] = cb_new; od[r] = d_; oo[r] = o_;

            const float cdn = cb_new + (c_new - cb_new) * __expf(-d_ * dtn);
            const float hn = o_ * tanhf_(cdn);
            cdecr[r] = cdn;
            cbarr[r] = cb_new;
            hq |= ((unsigned long long)(unsigned short)f2bf(hn)) << (16 * r);
        }

        // ---- publish h_{t+1}: store; drain own wave's VMEM (vmcnt 0);
        //      then ONE block flag into 8 replicas ----
        if (t + 1 < TT) {
            unsigned long long* hout = (t & 1) ? h0 : h1;
            __hip_atomic_store(&hout[((size_t)b * HH + hcolBase) >> 2], hq,
                               __ATOMIC_RELAXED, __HIP_MEMORY_SCOPE_AGENT);
            asm volatile("s_waitcnt vmcnt(0)" ::: "memory");
            if (lane < 8) {
                __hip_atomic_store(
                    &flags[(((size_t)t * NGRP + grp) * 8 + lane) * 32 + j0], 1u,
                    __ATOMIC_RELAXED, __HIP_MEMORY_SCOPE_AGENT);
            }
        }

        // ---- out stores (after flag; retire during next poll) ----
        const size_t ob = ((size_t)b * TT + t) * HH + hcolBase;
        *(f32x4*)(out + ob)         = oc;
        *(f32x4*)(out + ob + S)     = ocb;
        *(f32x4*)(out + ob + 2 * S) = od;
        *(f32x4*)(out + ob + 3 * S) = oo;

        #pragma unroll
        for (int g = 0; g < 7; ++g) xq[g] = xqn[g];
        dtn = dtnn;
    }
}

extern "C" void kernel_launch(void* const* d_in, const int* in_sizes, int n_in,
                              void* d_out, int out_size, void* d_ws, size_t ws_size,
                              hipStream_t stream) {
    const float* input = (const float*)d_in[0];  // (B, T, D)
    const float* dur   = (const float*)d_in[1];  // (B, T)
    const float* Wx    = (const float*)d_in[2];  // (D, 7H)
    const float* Wh    = (const float*)d_in[3];  // (H, 7H)
    const float* bias  = (const float*)d_in[4];  // (7H,)
    float* out = (float*)d_out;                  // (4, B, T, H)

    short* Xb  = (short*)d_ws;                       // 45,875,200 shorts
    short* Xbf = Xb + (size_t)TT * BB * NCOL;        // 3,276,800
    short* WxP = Xbf + (size_t)BB * TT * DD;         // 917,504
    short* WhP = WxP + 224 * 8 * 64 * 8;             // 1,835,008
    short* h0s = WhP + 32 * 7 * 16 * 64 * 8;         // 32,768
    short* h1s = h0s + BB * HH;                      // 32,768
    unsigned* flags = (unsigned*)(h1s + BB * HH);    // TT*NGRP*8*32 u32

    // flags must start zeroed every launch (h bufs never read before write)
    hipMemsetAsync(flags, 0, (size_t)TT * NGRP * 8 * 32 * sizeof(unsigned), stream);

    convert_x_kernel<<<3200, 256, 0, stream>>>(input, Xbf);
    pack_wx_kernel<<<3584, 256, 0, stream>>>(Wx, WxP);
    pack_wh_kernel<<<7168, 256, 0, stream>>>(Wh, WhP);

    precompute_kernel<<<dim3(28, 200), 256, 0, stream>>>(Xbf, WxP, bias, Xb);

    recurrent_kernel<<<NBLK, 64, 0, stream>>>(
        Xb, WhP, dur,
        (unsigned long long*)h0s, (unsigned long long*)h1s,
        flags, out);
}